// Round 5
// baseline (729.612 us; speedup 1.0000x reference)
//
#include <hip/hip_runtime.h>
#include <cstdint>

#define T_SEQ 512
#define BATCH 256
#define HID   32

// ---------- fast activations (fp32, saturating, NaN-free) ----------
__device__ __forceinline__ float rcp_fast(float x) {
    return __builtin_amdgcn_rcpf(x);
}
// sigmoid(x) = 1/(1+exp(-x)); x->-inf: exp->inf, rcp(inf)=0; x->+inf: 1.
__device__ __forceinline__ float sigf(float x) {
    return rcp_fast(1.0f + __expf(-x));
}
// tanh(x) = 2/(1+exp(-2x)) - 1; saturates correctly at +-inf, no clamp needed.
__device__ __forceinline__ float tanhf_fast(float x) {
    return fmaf(2.0f, rcp_fast(1.0f + __expf(-2.0f * x)), -1.0f);
}
__device__ __forceinline__ float rdlane(float v, int lane) {
    return __uint_as_float(__builtin_amdgcn_readlane(__float_as_uint(v), lane));
}

// ---------- half-wave swap: lane l <-> lane l^32 ----------
// Prefer gfx950 v_permlane32_swap_b32 (VALU pipe, ~4cyc) over __shfl_xor
// (ds_bpermute, LDS pipe, ~35cyc) — this sits on the per-step dependent path.
//
// SEMANTICS-AGNOSTIC COMBINE: the instruction swaps one half of vdst with the
// opposite half of vsrc (exact vdst/vsrc direction differs between doc
// sources). With both operands = z, each lane's returned pair (r.x, r.y)
// holds {own, partner} in SOME order; XOR identity own^partner^own = partner
// extracts the partner bit-exactly under either ordering. +1 VALU op vs a
// select — cheap insurance against a silent identity-swap bug.
#if defined(__has_builtin)
#  if __has_builtin(__builtin_amdgcn_permlane32_swap)
#    define HAVE_PLSWAP 1
#  endif
#endif
#ifndef HAVE_PLSWAP
#  define HAVE_PLSWAP 0
#endif

__device__ __forceinline__ float swap_half(float z) {
#if HAVE_PLSWAP
    typedef int int2v __attribute__((ext_vector_type(2)));
    unsigned zu = __float_as_uint(z);
    int2v r = __builtin_amdgcn_permlane32_swap((int)zu, (int)zu, false, false);
    return __uint_as_float((unsigned)r.x ^ (unsigned)r.y ^ zu);
#else
    return __shfl_xor(z, 32);
#endif
}

// =====================================================================
// LSTM layer 0: one wave64 per (direction, batch) recurrence.
// Lane l owns W_hh rows l (i/f) and 64+l (g/o). Input term (I=3) is
// software-pipelined: step s+1's x-contribution is computed during step s
// (independent of the h-chain), x loads prefetched 2 steps ahead.
// Writes h0[b][t][dir*32+u].
// =====================================================================
__global__ void __launch_bounds__(64)
lstm_l0(const float* __restrict__ x,        // [B][T][3]
        const float* __restrict__ wih_f, const float* __restrict__ whh_f,
        const float* __restrict__ bih_f, const float* __restrict__ bhh_f,
        const float* __restrict__ wih_b, const float* __restrict__ whh_b,
        const float* __restrict__ bih_b, const float* __restrict__ bhh_b,
        float* __restrict__ h0)             // [B][T][64]
{
    const int l   = threadIdx.x;            // 0..63
    const int u   = l & 31;
    const int hi  = l >> 5;                 // 0: i/g rows, 1: f/o rows
    const int bid = blockIdx.x;             // 0..511
    const int dir = bid >> 8;
    const int b   = bid & 255;

    const float* wih = dir ? wih_b : wih_f;
    const float* whh = dir ? whh_b : whh_f;
    const float* bih = dir ? bih_b : bih_f;
    const float* bhh = dir ? bhh_b : bhh_f;

    const int ra = l;                       // rows 0..63: gate i (hi=0) / f (hi=1)
    const int rb = 64 + l;                  // rows 64..127: gate g (hi=0) / o (hi=1)

    float wa[HID], wb[HID];
#pragma unroll
    for (int k = 0; k < HID; k += 4) {
        float4 va = *(const float4*)(whh + ra * HID + k);
        wa[k] = va.x; wa[k+1] = va.y; wa[k+2] = va.z; wa[k+3] = va.w;
        float4 vb = *(const float4*)(whh + rb * HID + k);
        wb[k] = vb.x; wb[k+1] = vb.y; wb[k+2] = vb.z; wb[k+3] = vb.w;
    }
    const float wia0 = wih[ra*3+0], wia1 = wih[ra*3+1], wia2 = wih[ra*3+2];
    const float wib0 = wih[rb*3+0], wib1 = wih[rb*3+1], wib2 = wih[rb*3+2];
    const float basa = bih[ra] + bhh[ra];
    const float basb = bih[rb] + bhh[rb];

    float hs[HID];                          // uniform (SGPR) copy of h
#pragma unroll
    for (int k = 0; k < HID; ++k) hs[k] = 0.0f;
    float c = 0.0f;

    const float* xb   = x  + (size_t)b * T_SEQ * 3;
    float*       outp = h0 + (size_t)b * T_SEQ * 64 + dir * HID + u;

    int t = dir ? (T_SEQ - 1) : 0;
    const int step = dir ? -1 : 1;

    // pipeline prologue: x-term for s=0 ready; x regs hold s=1's input
    float x0 = xb[t*3+0], x1 = xb[t*3+1], x2 = xb[t*3+2];
    float xga = fmaf(wia2, x2, fmaf(wia1, x1, fmaf(wia0, x0, basa)));
    float xgb = fmaf(wib2, x2, fmaf(wib1, x1, fmaf(wib0, x0, basb)));
    {
        int tn = t + step;
        x0 = xb[tn*3+0]; x1 = xb[tn*3+1]; x2 = xb[tn*3+2];
    }

    for (int s = 0; s < T_SEQ; ++s) {
        // x-term for step s+1 (independent of h-chain; fills latency slots)
        float xgaN = fmaf(wia2, x2, fmaf(wia1, x1, fmaf(wia0, x0, basa)));
        float xgbN = fmaf(wib2, x2, fmaf(wib1, x1, fmaf(wib0, x0, basb)));
        // prefetch x for step s+2 (uniform addr -> scalar loads)
        {
            int sn = (s + 2 < T_SEQ) ? (s + 2) : (T_SEQ - 1);
            int tn = dir ? (T_SEQ - 1 - sn) : sn;
            x0 = xb[tn*3+0]; x1 = xb[tn*3+1]; x2 = xb[tn*3+2];
        }

        float a0 = xga, a1 = 0.f, a2 = 0.f, a3 = 0.f;
        float c0 = xgb, c1 = 0.f, c2 = 0.f, c3 = 0.f;
#pragma unroll
        for (int k = 0; k < HID; k += 4) {
            a0 = fmaf(wa[k+0], hs[k+0], a0);
            a1 = fmaf(wa[k+1], hs[k+1], a1);
            a2 = fmaf(wa[k+2], hs[k+2], a2);
            a3 = fmaf(wa[k+3], hs[k+3], a3);
            c0 = fmaf(wb[k+0], hs[k+0], c0);
            c1 = fmaf(wb[k+1], hs[k+1], c1);
            c2 = fmaf(wb[k+2], hs[k+2], c2);
            c3 = fmaf(wb[k+3], hs[k+3], c3);
        }
        float za = (a0 + a1) + (a2 + a3);
        float zb = (c0 + c1) + (c2 + c3);

        // half-swap + branch-free gate select
        float fa = swap_half(za);
        float fb = swap_half(zb);
        float zi = hi ? fa : za;
        float zf = hi ? za : fa;
        float zg = hi ? fb : zb;
        float zo = hi ? zb : fb;

        c = sigf(zf) * c + sigf(zi) * tanhf_fast(zg);
        float h = sigf(zo) * tanhf_fast(c);

        if (hi == 0) outp[(size_t)t * 64] = h;

        // broadcast new h to uniform regs for next step
#pragma unroll
        for (int k = 0; k < HID; ++k) hs[k] = rdlane(h, k);

        xga = xgaN; xgb = xgbN;
        t += step;
    }
}

// =====================================================================
// gx1 = bias + h0 @ w_ih_l1^T for both directions.
// One block per t (512 blocks, 256 threads). Thread owns one output col
// (d,j) with its 64 W values in VGPRs; A row (h0[b][t][:]) is block-uniform,
// double-buffered in registers. Out layout: gx1[d][t][b][128].
// =====================================================================
__global__ void __launch_bounds__(256)
gx1_gemm(const float* __restrict__ h0,     // [B][T][64]
         const float* __restrict__ w_f, const float* __restrict__ bi_f, const float* __restrict__ bh_f,
         const float* __restrict__ w_b, const float* __restrict__ bi_b, const float* __restrict__ bh_b,
         float* __restrict__ gxo)          // [2][T][B][128]
{
    const int tid = threadIdx.x;
    const int d = tid >> 7, j = tid & 127;
    const int t = blockIdx.x;

    const float* w = d ? w_b : w_f;
    float wr[64];
#pragma unroll
    for (int k = 0; k < 64; k += 4) {
        float4 v = *(const float4*)(w + j*64 + k);
        wr[k] = v.x; wr[k+1] = v.y; wr[k+2] = v.z; wr[k+3] = v.w;
    }
    const float bias = d ? (bi_b[j] + bh_b[j]) : (bi_f[j] + bh_f[j]);

    float* outp = gxo + ((size_t)d * T_SEQ + t) * ((size_t)BATCH * 128) + j;
    const float* base = h0 + (size_t)t * 64;       // + b * (T*64)

    float4 A[16], B4[16];
#pragma unroll
    for (int q = 0; q < 16; ++q) A[q] = *(const float4*)(base + q*4);   // b=0

    for (int b = 0; b < BATCH; b += 2) {
        {   // prefetch row b+1
            const float* p = base + (size_t)(b + 1) * (T_SEQ * 64);
#pragma unroll
            for (int q = 0; q < 16; ++q) B4[q] = *(const float4*)(p + q*4);
        }
        {   // compute row b
            float a0 = bias, a1 = 0.f, a2 = 0.f, a3 = 0.f;
#pragma unroll
            for (int q = 0; q < 16; ++q) {
                a0 = fmaf(A[q].x, wr[4*q+0], a0);
                a1 = fmaf(A[q].y, wr[4*q+1], a1);
                a2 = fmaf(A[q].z, wr[4*q+2], a2);
                a3 = fmaf(A[q].w, wr[4*q+3], a3);
            }
            outp[(size_t)b * 128] = (a0 + a1) + (a2 + a3);
        }
        if (b + 2 < BATCH) {   // prefetch row b+2
            const float* p = base + (size_t)(b + 2) * (T_SEQ * 64);
#pragma unroll
            for (int q = 0; q < 16; ++q) A[q] = *(const float4*)(p + q*4);
        }
        {   // compute row b+1
            float a0 = bias, a1 = 0.f, a2 = 0.f, a3 = 0.f;
#pragma unroll
            for (int q = 0; q < 16; ++q) {
                a0 = fmaf(B4[q].x, wr[4*q+0], a0);
                a1 = fmaf(B4[q].y, wr[4*q+1], a1);
                a2 = fmaf(B4[q].z, wr[4*q+2], a2);
                a3 = fmaf(B4[q].w, wr[4*q+3], a3);
            }
            outp[(size_t)(b + 1) * 128] = (a0 + a1) + (a2 + a3);
        }
    }
}

// =====================================================================
// LSTM layer 1: same wave-per-recurrence structure; input term read from
// precomputed gx1. gx1 (134 MB) is L3-resident -> ~400-500cyc latency, so
// loads are prefetched TWO steps ahead (~2 steps ~ 500cyc of cover).
// Only final h written.
// =====================================================================
__global__ void __launch_bounds__(64)
lstm_l1(const float* __restrict__ gx,      // [2][T][B][128]
        const float* __restrict__ whh_f, const float* __restrict__ whh_b,
        float* __restrict__ hn)            // [B][64]
{
    const int l   = threadIdx.x;
    const int u   = l & 31;
    const int hi  = l >> 5;
    const int bid = blockIdx.x;
    const int dir = bid >> 8;
    const int b   = bid & 255;

    const float* whh = dir ? whh_b : whh_f;
    const int ra = l, rb = 64 + l;

    float wa[HID], wb[HID];
#pragma unroll
    for (int k = 0; k < HID; k += 4) {
        float4 va = *(const float4*)(whh + ra * HID + k);
        wa[k] = va.x; wa[k+1] = va.y; wa[k+2] = va.z; wa[k+3] = va.w;
        float4 vb = *(const float4*)(whh + rb * HID + k);
        wb[k] = vb.x; wb[k+1] = vb.y; wb[k+2] = vb.z; wb[k+3] = vb.w;
    }

    float hs[HID];
#pragma unroll
    for (int k = 0; k < HID; ++k) hs[k] = 0.0f;
    float c = 0.0f;

    const size_t TS = (size_t)BATCH * 128;
    const float* gp = gx + ((size_t)dir * T_SEQ * BATCH + b) * 128;

    int t = dir ? (T_SEQ - 1) : 0;
    const int step = dir ? -1 : 1;

    // distance-2 prefetch pipeline: ga0/gb0 for step s, ga1/gb1 for s+1
    float ga0 = gp[(size_t)t * TS + ra];
    float gb0 = gp[(size_t)t * TS + rb];
    float ga1, gb1;
    {
        int t1 = t + step;
        ga1 = gp[(size_t)t1 * TS + ra];
        gb1 = gp[(size_t)t1 * TS + rb];
    }

    float h = 0.0f;
    for (int s = 0; s < T_SEQ; ++s) {
        // issue loads for step s+2 (coalesced 256B per wave)
        float gaN, gbN;
        {
            int sn = (s + 2 < T_SEQ) ? (s + 2) : (T_SEQ - 1);
            int tn = dir ? (T_SEQ - 1 - sn) : sn;
            gaN = gp[(size_t)tn * TS + ra];
            gbN = gp[(size_t)tn * TS + rb];
        }

        float a0 = ga0, a1 = 0.f, a2 = 0.f, a3 = 0.f;
        float c0 = gb0, c1 = 0.f, c2 = 0.f, c3 = 0.f;
#pragma unroll
        for (int k = 0; k < HID; k += 4) {
            a0 = fmaf(wa[k+0], hs[k+0], a0);
            a1 = fmaf(wa[k+1], hs[k+1], a1);
            a2 = fmaf(wa[k+2], hs[k+2], a2);
            a3 = fmaf(wa[k+3], hs[k+3], a3);
            c0 = fmaf(wb[k+0], hs[k+0], c0);
            c1 = fmaf(wb[k+1], hs[k+1], c1);
            c2 = fmaf(wb[k+2], hs[k+2], c2);
            c3 = fmaf(wb[k+3], hs[k+3], c3);
        }
        float za = (a0 + a1) + (a2 + a3);
        float zb = (c0 + c1) + (c2 + c3);

        float fa = swap_half(za);
        float fb = swap_half(zb);
        float zi = hi ? fa : za;
        float zf = hi ? za : fa;
        float zg = hi ? fb : zb;
        float zo = hi ? zb : fb;

        c = sigf(zf) * c + sigf(zi) * tanhf_fast(zg);
        h = sigf(zo) * tanhf_fast(c);

#pragma unroll
        for (int k = 0; k < HID; ++k) hs[k] = rdlane(h, k);

        ga0 = ga1; gb0 = gb1; ga1 = gaN; gb1 = gbN;
        t += step;
    }
    if (hi == 0) hn[(size_t)b * 64 + dir * HID + u] = h;
}

// =====================================================================
// Classifier: relu(hn @ wc1^T + bc1) @ wc2^T + bc2. One block per batch.
// =====================================================================
__global__ void __launch_bounds__(64)
classifier(const float* __restrict__ hn,   // [B][64]
           const float* __restrict__ wc1,  // [32][64]
           const float* __restrict__ bc1,  // [32]
           const float* __restrict__ wc2,  // [2][32]
           const float* __restrict__ bc2,  // [2]
           float* __restrict__ out)        // [B][2]
{
    const int b = blockIdx.x, tid = threadIdx.x;
    __shared__ float hsm[64];
    __shared__ float hidden[32];
    hsm[tid] = hn[(size_t)b * 64 + tid];
    __syncthreads();
    if (tid < 32) {
        float a = bc1[tid];
#pragma unroll
        for (int k = 0; k < 64; ++k) a = fmaf(wc1[tid*64 + k], hsm[k], a);
        hidden[tid] = fmaxf(a, 0.0f);
    }
    __syncthreads();
    if (tid < 2) {
        float a = bc2[tid];
#pragma unroll
        for (int k = 0; k < 32; ++k) a = fmaf(wc2[tid*32 + k], hidden[k], a);
        out[(size_t)b * 2 + tid] = a;
    }
}

// =====================================================================
extern "C" void kernel_launch(void* const* d_in, const int* in_sizes, int n_in,
                              void* d_out, int out_size, void* d_ws, size_t ws_size,
                              hipStream_t stream) {
    const float* x        = (const float*)d_in[0];
    const float* w_ih_l0f = (const float*)d_in[1];
    const float* w_hh_l0f = (const float*)d_in[2];
    const float* b_ih_l0f = (const float*)d_in[3];
    const float* b_hh_l0f = (const float*)d_in[4];
    const float* w_ih_l0b = (const float*)d_in[5];
    const float* w_hh_l0b = (const float*)d_in[6];
    const float* b_ih_l0b = (const float*)d_in[7];
    const float* b_hh_l0b = (const float*)d_in[8];
    const float* w_ih_l1f = (const float*)d_in[9];
    const float* w_hh_l1f = (const float*)d_in[10];
    const float* b_ih_l1f = (const float*)d_in[11];
    const float* b_hh_l1f = (const float*)d_in[12];
    const float* w_ih_l1b = (const float*)d_in[13];
    const float* w_hh_l1b = (const float*)d_in[14];
    const float* b_ih_l1b = (const float*)d_in[15];
    const float* b_hh_l1b = (const float*)d_in[16];
    const float* wc1      = (const float*)d_in[17];
    const float* bc1      = (const float*)d_in[18];
    const float* wc2      = (const float*)d_in[19];
    const float* bc2      = (const float*)d_in[20];
    float* out = (float*)d_out;

    // workspace layout (bytes):
    //   h0  [B][T][64]      : 33,554,432
    //   gx1 [2][T][B][128]  : 134,217,728
    //   hn  [B][64]         : 65,536
    char* ws = (char*)d_ws;
    float* h0  = (float*)(ws);
    float* gx1 = (float*)(ws + 33554432);
    float* hn  = (float*)(ws + 33554432 + 134217728);

    lstm_l0<<<dim3(512), dim3(64), 0, stream>>>(
        x, w_ih_l0f, w_hh_l0f, b_ih_l0f, b_hh_l0f,
           w_ih_l0b, w_hh_l0b, b_ih_l0b, b_hh_l0b, h0);

    gx1_gemm<<<dim3(T_SEQ), dim3(256), 0, stream>>>(
        h0, w_ih_l1f, b_ih_l1f, b_hh_l1f,
            w_ih_l1b, b_ih_l1b, b_hh_l1b, gx1);

    lstm_l1<<<dim3(512), dim3(64), 0, stream>>>(
        gx1, w_hh_l1f, w_hh_l1b, hn);

    classifier<<<dim3(BATCH), dim3(64), 0, stream>>>(
        hn, wc1, bc1, wc2, bc2, out);
}

// Round 6
// 729.332 us; speedup vs baseline: 1.0004x; 1.0004x over previous
//
#include <hip/hip_runtime.h>
#include <cstdint>

#define T_SEQ 512
#define BATCH 256
#define HID   32

// ---------- fast activations (fp32, saturating, NaN-free) ----------
__device__ __forceinline__ float rcp_fast(float x) {
    return __builtin_amdgcn_rcpf(x);
}
// sigmoid(x) = 1/(1+exp(-x)); x->-inf: exp->inf, rcp(inf)=0; x->+inf: 1.
__device__ __forceinline__ float sigf(float x) {
    return rcp_fast(1.0f + __expf(-x));
}
// tanh(x) = 2/(1+exp(-2x)) - 1; saturates correctly at +-inf, no clamp needed.
__device__ __forceinline__ float tanhf_fast(float x) {
    return fmaf(2.0f, rcp_fast(1.0f + __expf(-2.0f * x)), -1.0f);
}
__device__ __forceinline__ float rdlane(float v, int lane) {
    return __uint_as_float(__builtin_amdgcn_readlane(__float_as_uint(v), lane));
}

// ---------- half-wave swap: lane l <-> lane l^32 ----------
// v_permlane32_swap_b32 (VALU pipe) instead of __shfl_xor (LDS pipe) — this
// sits on the per-step dependent path. Semantics-agnostic XOR combine: with
// both operands = z, the returned pair holds {own, partner} in some order;
// own^r.x^r.y = partner bit-exactly under either vdst/vsrc convention.
#if defined(__has_builtin)
#  if __has_builtin(__builtin_amdgcn_permlane32_swap)
#    define HAVE_PLSWAP 1
#  endif
#endif
#ifndef HAVE_PLSWAP
#  define HAVE_PLSWAP 0
#endif

__device__ __forceinline__ float swap_half(float z) {
#if HAVE_PLSWAP
    typedef int int2v __attribute__((ext_vector_type(2)));
    unsigned zu = __float_as_uint(z);
    int2v r = __builtin_amdgcn_permlane32_swap((int)zu, (int)zu, false, false);
    return __uint_as_float((unsigned)r.x ^ (unsigned)r.y ^ zu);
#else
    return __shfl_xor(z, 32);
#endif
}

#define LD4(p) (*(const float4*)(p))

// One K-slice of the hidden matvec: 4 i/f-row FMAs + 4 g/o-row FMAs.
// hs[] is wave-uniform (SGPR file); WA/WB are resident float4 VGPRs.
#define HFMA(WA, WB, k0)                                            \
    a0 = fmaf(WA.x, hs[k0+0], a0);                                  \
    a1 = fmaf(WA.y, hs[k0+1], a1);                                  \
    a2 = fmaf(WA.z, hs[k0+2], a2);                                  \
    a3 = fmaf(WA.w, hs[k0+3], a3);                                  \
    c0 = fmaf(WB.x, hs[k0+0], c0);                                  \
    c1 = fmaf(WB.y, hs[k0+1], c1);                                  \
    c2 = fmaf(WB.z, hs[k0+2], c2);                                  \
    c3 = fmaf(WB.w, hs[k0+3], c3);

#define HFMA_ALL                                                    \
    HFMA(wa0, wb0,  0) HFMA(wa1, wb1,  4)                           \
    HFMA(wa2, wb2,  8) HFMA(wa3, wb3, 12)                           \
    HFMA(wa4, wb4, 16) HFMA(wa5, wb5, 20)                           \
    HFMA(wa6, wb6, 24) HFMA(wa7, wb7, 28)

// Declare + load the per-lane weight fragments as explicit float4 scalars
// (NOT an array): guarantees SROA keeps them in VGPRs. (64,1) launch bound
// lifts the default occupancy-driven VGPR cap (round-5 profile: VGPR=44 ->
// the 64 resident weights were spilled to scratch; 1250 cyc/step, VALU 19%.)
#define WLOAD(whh_)                                                 \
    float4 wa0 = LD4((whh_) + ra*HID +  0),                         \
           wa1 = LD4((whh_) + ra*HID +  4),                         \
           wa2 = LD4((whh_) + ra*HID +  8),                         \
           wa3 = LD4((whh_) + ra*HID + 12),                         \
           wa4 = LD4((whh_) + ra*HID + 16),                         \
           wa5 = LD4((whh_) + ra*HID + 20),                         \
           wa6 = LD4((whh_) + ra*HID + 24),                         \
           wa7 = LD4((whh_) + ra*HID + 28);                         \
    float4 wb0 = LD4((whh_) + rb*HID +  0),                         \
           wb1 = LD4((whh_) + rb*HID +  4),                         \
           wb2 = LD4((whh_) + rb*HID +  8),                         \
           wb3 = LD4((whh_) + rb*HID + 12),                         \
           wb4 = LD4((whh_) + rb*HID + 16),                         \
           wb5 = LD4((whh_) + rb*HID + 20),                         \
           wb6 = LD4((whh_) + rb*HID + 24),                         \
           wb7 = LD4((whh_) + rb*HID + 28);

// =====================================================================
// LSTM layer 0: one wave64 per (direction, batch) recurrence.
// Lane l owns W_hh rows l (i/f) and 64+l (g/o). Input term (I=3) is
// software-pipelined one step ahead. Writes h0[b][t][dir*32+u].
// =====================================================================
__global__ void __launch_bounds__(64, 1)
lstm_l0(const float* __restrict__ x,        // [B][T][3]
        const float* __restrict__ wih_f, const float* __restrict__ whh_f,
        const float* __restrict__ bih_f, const float* __restrict__ bhh_f,
        const float* __restrict__ wih_b, const float* __restrict__ whh_b,
        const float* __restrict__ bih_b, const float* __restrict__ bhh_b,
        float* __restrict__ h0)             // [B][T][64]
{
    const int l   = threadIdx.x;            // 0..63
    const int u   = l & 31;
    const int hi  = l >> 5;                 // 0: i/g rows, 1: f/o rows
    const int bid = blockIdx.x;             // 0..511
    const int dir = bid >> 8;
    const int b   = bid & 255;

    const float* wih = dir ? wih_b : wih_f;
    const float* whh = dir ? whh_b : whh_f;
    const float* bih = dir ? bih_b : bih_f;
    const float* bhh = dir ? bhh_b : bhh_f;

    const int ra = l;                       // rows 0..63: gate i (hi=0) / f (hi=1)
    const int rb = 64 + l;                  // rows 64..127: gate g (hi=0) / o (hi=1)

    WLOAD(whh)

    const float wia0 = wih[ra*3+0], wia1 = wih[ra*3+1], wia2 = wih[ra*3+2];
    const float wib0 = wih[rb*3+0], wib1 = wih[rb*3+1], wib2 = wih[rb*3+2];
    const float basa = bih[ra] + bhh[ra];
    const float basb = bih[rb] + bhh[rb];

    float hs[HID];                          // wave-uniform -> SGPR file
#pragma unroll
    for (int k = 0; k < HID; ++k) hs[k] = 0.0f;
    float c = 0.0f;

    const float* xb   = x  + (size_t)b * T_SEQ * 3;
    float*       outp = h0 + (size_t)b * T_SEQ * 64 + dir * HID + u;

    int t = dir ? (T_SEQ - 1) : 0;
    const int step = dir ? -1 : 1;

    // pipeline prologue: x-term for s=0 ready; x regs hold s=1's input
    float x0 = xb[t*3+0], x1 = xb[t*3+1], x2 = xb[t*3+2];
    float xga = fmaf(wia2, x2, fmaf(wia1, x1, fmaf(wia0, x0, basa)));
    float xgb = fmaf(wib2, x2, fmaf(wib1, x1, fmaf(wib0, x0, basb)));
    {
        int tn = t + step;
        x0 = xb[tn*3+0]; x1 = xb[tn*3+1]; x2 = xb[tn*3+2];
    }

    for (int s = 0; s < T_SEQ; ++s) {
        // x-term for step s+1 (independent of h-chain; fills latency slots)
        float xgaN = fmaf(wia2, x2, fmaf(wia1, x1, fmaf(wia0, x0, basa)));
        float xgbN = fmaf(wib2, x2, fmaf(wib1, x1, fmaf(wib0, x0, basb)));
        // prefetch x for step s+2 (uniform addr -> scalar loads)
        {
            int sn = (s + 2 < T_SEQ) ? (s + 2) : (T_SEQ - 1);
            int tn = dir ? (T_SEQ - 1 - sn) : sn;
            x0 = xb[tn*3+0]; x1 = xb[tn*3+1]; x2 = xb[tn*3+2];
        }

        float a0 = xga, a1 = 0.f, a2 = 0.f, a3 = 0.f;
        float c0 = xgb, c1 = 0.f, c2 = 0.f, c3 = 0.f;
        HFMA_ALL
        float za = (a0 + a1) + (a2 + a3);
        float zb = (c0 + c1) + (c2 + c3);

        // half-swap + branch-free gate select
        float fa = swap_half(za);
        float fb = swap_half(zb);
        float zi = hi ? fa : za;
        float zf = hi ? za : fa;
        float zg = hi ? fb : zb;
        float zo = hi ? zb : fb;

        c = sigf(zf) * c + sigf(zi) * tanhf_fast(zg);
        float h = sigf(zo) * tanhf_fast(c);

        if (hi == 0) outp[(size_t)t * 64] = h;

        // broadcast new h to uniform regs for next step
#pragma unroll
        for (int k = 0; k < HID; ++k) hs[k] = rdlane(h, k);

        xga = xgaN; xgb = xgbN;
        t += step;
    }
}

// =====================================================================
// gx1 = bias + h0 @ w_ih_l1^T for both directions.
// One block per t (512 blocks, 256 threads). Thread owns one output col
// (d,j) with its 64 W values in VGPRs; A row (h0[b][t][:]) is block-uniform,
// double-buffered in registers. Out layout: gx1[d][t][b][128].
// (256,2): 256-VGPR cap fits the ~210 live regs AND keeps 2 blocks/CU.
// =====================================================================
__global__ void __launch_bounds__(256, 2)
gx1_gemm(const float* __restrict__ h0,     // [B][T][64]
         const float* __restrict__ w_f, const float* __restrict__ bi_f, const float* __restrict__ bh_f,
         const float* __restrict__ w_b, const float* __restrict__ bi_b, const float* __restrict__ bh_b,
         float* __restrict__ gxo)          // [2][T][B][128]
{
    const int tid = threadIdx.x;
    const int d = tid >> 7, j = tid & 127;
    const int t = blockIdx.x;

    const float* w = d ? w_b : w_f;
    float wr[64];
#pragma unroll
    for (int k = 0; k < 64; k += 4) {
        float4 v = LD4(w + j*64 + k);
        wr[k] = v.x; wr[k+1] = v.y; wr[k+2] = v.z; wr[k+3] = v.w;
    }
    const float bias = d ? (bi_b[j] + bh_b[j]) : (bi_f[j] + bh_f[j]);

    float* outp = gxo + ((size_t)d * T_SEQ + t) * ((size_t)BATCH * 128) + j;
    const float* base = h0 + (size_t)t * 64;       // + b * (T*64)

    float4 A[16], B4[16];
#pragma unroll
    for (int q = 0; q < 16; ++q) A[q] = LD4(base + q*4);   // b=0

    for (int b = 0; b < BATCH; b += 2) {
        {   // prefetch row b+1
            const float* p = base + (size_t)(b + 1) * (T_SEQ * 64);
#pragma unroll
            for (int q = 0; q < 16; ++q) B4[q] = LD4(p + q*4);
        }
        {   // compute row b
            float a0 = bias, a1 = 0.f, a2 = 0.f, a3 = 0.f;
#pragma unroll
            for (int q = 0; q < 16; ++q) {
                a0 = fmaf(A[q].x, wr[4*q+0], a0);
                a1 = fmaf(A[q].y, wr[4*q+1], a1);
                a2 = fmaf(A[q].z, wr[4*q+2], a2);
                a3 = fmaf(A[q].w, wr[4*q+3], a3);
            }
            outp[(size_t)b * 128] = (a0 + a1) + (a2 + a3);
        }
        if (b + 2 < BATCH) {   // prefetch row b+2
            const float* p = base + (size_t)(b + 2) * (T_SEQ * 64);
#pragma unroll
            for (int q = 0; q < 16; ++q) A[q] = LD4(p + q*4);
        }
        {   // compute row b+1
            float a0 = bias, a1 = 0.f, a2 = 0.f, a3 = 0.f;
#pragma unroll
            for (int q = 0; q < 16; ++q) {
                a0 = fmaf(B4[q].x, wr[4*q+0], a0);
                a1 = fmaf(B4[q].y, wr[4*q+1], a1);
                a2 = fmaf(B4[q].z, wr[4*q+2], a2);
                a3 = fmaf(B4[q].w, wr[4*q+3], a3);
            }
            outp[(size_t)(b + 1) * 128] = (a0 + a1) + (a2 + a3);
        }
    }
}

// =====================================================================
// LSTM layer 1: same wave-per-recurrence structure; input term read from
// precomputed gx1 (L3-resident, ~400-500cyc) -> distance-2 prefetch.
// Only final h written.
// =====================================================================
__global__ void __launch_bounds__(64, 1)
lstm_l1(const float* __restrict__ gx,      // [2][T][B][128]
        const float* __restrict__ whh_f, const float* __restrict__ whh_b,
        float* __restrict__ hn)            // [B][64]
{
    const int l   = threadIdx.x;
    const int u   = l & 31;
    const int hi  = l >> 5;
    const int bid = blockIdx.x;
    const int dir = bid >> 8;
    const int b   = bid & 255;

    const float* whh = dir ? whh_b : whh_f;
    const int ra = l, rb = 64 + l;

    WLOAD(whh)

    float hs[HID];
#pragma unroll
    for (int k = 0; k < HID; ++k) hs[k] = 0.0f;
    float c = 0.0f;

    const size_t TS = (size_t)BATCH * 128;
    const float* gp = gx + ((size_t)dir * T_SEQ * BATCH + b) * 128;

    int t = dir ? (T_SEQ - 1) : 0;
    const int step = dir ? -1 : 1;

    // distance-2 prefetch pipeline: ga0/gb0 for step s, ga1/gb1 for s+1
    float ga0 = gp[(size_t)t * TS + ra];
    float gb0 = gp[(size_t)t * TS + rb];
    float ga1, gb1;
    {
        int t1 = t + step;
        ga1 = gp[(size_t)t1 * TS + ra];
        gb1 = gp[(size_t)t1 * TS + rb];
    }

    float h = 0.0f;
    for (int s = 0; s < T_SEQ; ++s) {
        // issue loads for step s+2 (coalesced 256B per wave)
        float gaN, gbN;
        {
            int sn = (s + 2 < T_SEQ) ? (s + 2) : (T_SEQ - 1);
            int tn = dir ? (T_SEQ - 1 - sn) : sn;
            gaN = gp[(size_t)tn * TS + ra];
            gbN = gp[(size_t)tn * TS + rb];
        }

        float a0 = ga0, a1 = 0.f, a2 = 0.f, a3 = 0.f;
        float c0 = gb0, c1 = 0.f, c2 = 0.f, c3 = 0.f;
        HFMA_ALL
        float za = (a0 + a1) + (a2 + a3);
        float zb = (c0 + c1) + (c2 + c3);

        float fa = swap_half(za);
        float fb = swap_half(zb);
        float zi = hi ? fa : za;
        float zf = hi ? za : fa;
        float zg = hi ? fb : zb;
        float zo = hi ? zb : fb;

        c = sigf(zf) * c + sigf(zi) * tanhf_fast(zg);
        h = sigf(zo) * tanhf_fast(c);

#pragma unroll
        for (int k = 0; k < HID; ++k) hs[k] = rdlane(h, k);

        ga0 = ga1; gb0 = gb1; ga1 = gaN; gb1 = gbN;
        t += step;
    }
    if (hi == 0) hn[(size_t)b * 64 + dir * HID + u] = h;
}

// =====================================================================
// Classifier: relu(hn @ wc1^T + bc1) @ wc2^T + bc2. One block per batch.
// =====================================================================
__global__ void __launch_bounds__(64)
classifier(const float* __restrict__ hn,   // [B][64]
           const float* __restrict__ wc1,  // [32][64]
           const float* __restrict__ bc1,  // [32]
           const float* __restrict__ wc2,  // [2][32]
           const float* __restrict__ bc2,  // [2]
           float* __restrict__ out)        // [B][2]
{
    const int b = blockIdx.x, tid = threadIdx.x;
    __shared__ float hsm[64];
    __shared__ float hidden[32];
    hsm[tid] = hn[(size_t)b * 64 + tid];
    __syncthreads();
    if (tid < 32) {
        float a = bc1[tid];
#pragma unroll
        for (int k = 0; k < 64; ++k) a = fmaf(wc1[tid*64 + k], hsm[k], a);
        hidden[tid] = fmaxf(a, 0.0f);
    }
    __syncthreads();
    if (tid < 2) {
        float a = bc2[tid];
#pragma unroll
        for (int k = 0; k < 32; ++k) a = fmaf(wc2[tid*32 + k], hidden[k], a);
        out[(size_t)b * 2 + tid] = a;
    }
}

// =====================================================================
extern "C" void kernel_launch(void* const* d_in, const int* in_sizes, int n_in,
                              void* d_out, int out_size, void* d_ws, size_t ws_size,
                              hipStream_t stream) {
    const float* x        = (const float*)d_in[0];
    const float* w_ih_l0f = (const float*)d_in[1];
    const float* w_hh_l0f = (const float*)d_in[2];
    const float* b_ih_l0f = (const float*)d_in[3];
    const float* b_hh_l0f = (const float*)d_in[4];
    const float* w_ih_l0b = (const float*)d_in[5];
    const float* w_hh_l0b = (const float*)d_in[6];
    const float* b_ih_l0b = (const float*)d_in[7];
    const float* b_hh_l0b = (const float*)d_in[8];
    const float* w_ih_l1f = (const float*)d_in[9];
    const float* w_hh_l1f = (const float*)d_in[10];
    const float* b_ih_l1f = (const float*)d_in[11];
    const float* b_hh_l1f = (const float*)d_in[12];
    const float* w_ih_l1b = (const float*)d_in[13];
    const float* w_hh_l1b = (const float*)d_in[14];
    const float* b_ih_l1b = (const float*)d_in[15];
    const float* b_hh_l1b = (const float*)d_in[16];
    const float* wc1      = (const float*)d_in[17];
    const float* bc1      = (const float*)d_in[18];
    const float* wc2      = (const float*)d_in[19];
    const float* bc2      = (const float*)d_in[20];
    float* out = (float*)d_out;

    // workspace layout (bytes):
    //   h0  [B][T][64]      : 33,554,432
    //   gx1 [2][T][B][128]  : 134,217,728
    //   hn  [B][64]         : 65,536
    char* ws = (char*)d_ws;
    float* h0  = (float*)(ws);
    float* gx1 = (float*)(ws + 33554432);
    float* hn  = (float*)(ws + 33554432 + 134217728);

    lstm_l0<<<dim3(512), dim3(64), 0, stream>>>(
        x, w_ih_l0f, w_hh_l0f, b_ih_l0f, b_hh_l0f,
           w_ih_l0b, w_hh_l0b, b_ih_l0b, b_hh_l0b, h0);

    gx1_gemm<<<dim3(T_SEQ), dim3(256), 0, stream>>>(
        h0, w_ih_l1f, b_ih_l1f, b_hh_l1f,
            w_ih_l1b, b_ih_l1b, b_hh_l1b, gx1);

    lstm_l1<<<dim3(512), dim3(64), 0, stream>>>(
        gx1, w_hh_l1f, w_hh_l1b, hn);

    classifier<<<dim3(BATCH), dim3(64), 0, stream>>>(
        hn, wc1, bc1, wc2, bc2, out);
}

// Round 7
// 681.570 us; speedup vs baseline: 1.0705x; 1.0701x over previous
//
#include <hip/hip_runtime.h>
#include <cstdint>

#define T_SEQ 512
#define BATCH 256
#define HID   32

// ---------- fast activations (fp32, saturating, NaN-free) ----------
__device__ __forceinline__ float rcp_fast(float x) {
    return __builtin_amdgcn_rcpf(x);
}
__device__ __forceinline__ float sigf(float x) {
    return rcp_fast(1.0f + __expf(-x));
}
__device__ __forceinline__ float tanhf_fast(float x) {
    return fmaf(2.0f, rcp_fast(1.0f + __expf(-2.0f * x)), -1.0f);
}
__device__ __forceinline__ float rdlane(float v, int lane) {
    return __uint_as_float(__builtin_amdgcn_readlane(__float_as_uint(v), lane));
}

// ---------- half-wave swap: lane l <-> lane l^32 ----------
#if defined(__has_builtin)
#  if __has_builtin(__builtin_amdgcn_permlane32_swap)
#    define HAVE_PLSWAP 1
#  endif
#endif
#ifndef HAVE_PLSWAP
#  define HAVE_PLSWAP 0
#endif

__device__ __forceinline__ float swap_half(float z) {
#if HAVE_PLSWAP
    typedef int int2v __attribute__((ext_vector_type(2)));
    unsigned zu = __float_as_uint(z);
    int2v r = __builtin_amdgcn_permlane32_swap((int)zu, (int)zu, false, false);
    return __uint_as_float((unsigned)r.x ^ (unsigned)r.y ^ zu);
#else
    return __shfl_xor(z, 32);
#endif
}

#define LD4(p) (*(const float4*)(p))

// Declare 4 named scalar floats from one float4 load (never an array -> SROA-proof).
#define WGRP(NM, PTR, OFF)                                                   \
    float NM##0, NM##1, NM##2, NM##3;                                        \
    { float4 _t = LD4((PTR) + (OFF)); NM##0 = _t.x; NM##1 = _t.y;            \
      NM##2 = _t.z; NM##3 = _t.w; }

// Force-live keepalive: requires the 4 values to sit in VGPRs at this point.
// Round-5/6 profile: VGPR_Count=44 -> RA targeted ~11 waves/EU occupancy and
// rematerialized the weight loads INTO the loop (L1 reload every step, ~1000
// cyc/step stall). Empty volatile asm each iteration makes keep-live the only
// cheap option; amdgpu_waves_per_eu lifts the budget so it is free.
#define KEEP4(NM)                                                            \
    asm volatile("" : "+v"(NM##0), "+v"(NM##1), "+v"(NM##2), "+v"(NM##3));

#define WLOAD_ALL(whh_)                                                      \
    WGRP(wa0_, whh_, ra*HID+ 0) WGRP(wa1_, whh_, ra*HID+ 4)                  \
    WGRP(wa2_, whh_, ra*HID+ 8) WGRP(wa3_, whh_, ra*HID+12)                  \
    WGRP(wa4_, whh_, ra*HID+16) WGRP(wa5_, whh_, ra*HID+20)                  \
    WGRP(wa6_, whh_, ra*HID+24) WGRP(wa7_, whh_, ra*HID+28)                  \
    WGRP(wb0_, whh_, rb*HID+ 0) WGRP(wb1_, whh_, rb*HID+ 4)                  \
    WGRP(wb2_, whh_, rb*HID+ 8) WGRP(wb3_, whh_, rb*HID+12)                  \
    WGRP(wb4_, whh_, rb*HID+16) WGRP(wb5_, whh_, rb*HID+20)                  \
    WGRP(wb6_, whh_, rb*HID+24) WGRP(wb7_, whh_, rb*HID+28)

#define KEEPW                                                                \
    KEEP4(wa0_) KEEP4(wa1_) KEEP4(wa2_) KEEP4(wa3_)                          \
    KEEP4(wa4_) KEEP4(wa5_) KEEP4(wa6_) KEEP4(wa7_)                          \
    KEEP4(wb0_) KEEP4(wb1_) KEEP4(wb2_) KEEP4(wb3_)                          \
    KEEP4(wb4_) KEEP4(wb5_) KEEP4(wb6_) KEEP4(wb7_)

#define HF(NMA, NMB, k)                                                      \
    a0 = fmaf(NMA##0, hs[(k)+0], a0); a1 = fmaf(NMA##1, hs[(k)+1], a1);      \
    a2 = fmaf(NMA##2, hs[(k)+2], a2); a3 = fmaf(NMA##3, hs[(k)+3], a3);      \
    c0 = fmaf(NMB##0, hs[(k)+0], c0); c1 = fmaf(NMB##1, hs[(k)+1], c1);      \
    c2 = fmaf(NMB##2, hs[(k)+2], c2); c3 = fmaf(NMB##3, hs[(k)+3], c3);

#define HFMA_ALL                                                             \
    HF(wa0_, wb0_,  0) HF(wa1_, wb1_,  4) HF(wa2_, wb2_,  8)                 \
    HF(wa3_, wb3_, 12) HF(wa4_, wb4_, 16) HF(wa5_, wb5_, 20)                 \
    HF(wa6_, wb6_, 24) HF(wa7_, wb7_, 28)

// =====================================================================
// LSTM layer 0: one wave64 per (direction, batch) recurrence.
// =====================================================================
__global__ void __launch_bounds__(64)
__attribute__((amdgpu_waves_per_eu(1, 1)))
lstm_l0(const float* __restrict__ x,        // [B][T][3]
        const float* __restrict__ wih_f, const float* __restrict__ whh_f,
        const float* __restrict__ bih_f, const float* __restrict__ bhh_f,
        const float* __restrict__ wih_b, const float* __restrict__ whh_b,
        const float* __restrict__ bih_b, const float* __restrict__ bhh_b,
        float* __restrict__ h0)             // [B][T][64]
{
    const int l   = threadIdx.x;            // 0..63
    const int u   = l & 31;
    const int hi  = l >> 5;                 // 0: i/g rows, 1: f/o rows
    const int bid = blockIdx.x;             // 0..511
    const int dir = bid >> 8;
    const int b   = bid & 255;

    const float* wih = dir ? wih_b : wih_f;
    const float* whh = dir ? whh_b : whh_f;
    const float* bih = dir ? bih_b : bih_f;
    const float* bhh = dir ? bhh_b : bhh_f;

    const int ra = l;                       // rows 0..63: gate i (hi=0) / f (hi=1)
    const int rb = 64 + l;                  // rows 64..127: gate g (hi=0) / o (hi=1)

    WLOAD_ALL(whh)

    float wia0 = wih[ra*3+0], wia1 = wih[ra*3+1], wia2 = wih[ra*3+2];
    float wib0 = wih[rb*3+0], wib1 = wih[rb*3+1], wib2 = wih[rb*3+2];
    float basa = bih[ra] + bhh[ra];
    float basb = bih[rb] + bhh[rb];

    float hs[HID];                          // wave-uniform -> SGPR file
#pragma unroll
    for (int k = 0; k < HID; ++k) hs[k] = 0.0f;
    float c = 0.0f;

    const float* xb   = x  + (size_t)b * T_SEQ * 3;
    float*       outp = h0 + (size_t)b * T_SEQ * 64 + dir * HID + u;

    int t = dir ? (T_SEQ - 1) : 0;
    const int step = dir ? -1 : 1;

    // pipeline prologue: x-term for s=0 ready; x regs hold s=1's input
    float x0 = xb[t*3+0], x1 = xb[t*3+1], x2 = xb[t*3+2];
    float xga = fmaf(wia2, x2, fmaf(wia1, x1, fmaf(wia0, x0, basa)));
    float xgb = fmaf(wib2, x2, fmaf(wib1, x1, fmaf(wib0, x0, basb)));
    {
        int tn = t + step;
        x0 = xb[tn*3+0]; x1 = xb[tn*3+1]; x2 = xb[tn*3+2];
    }

    for (int s = 0; s < T_SEQ; ++s) {
        KEEPW
        asm volatile("" : "+v"(wia0), "+v"(wia1), "+v"(wia2), "+v"(basa));
        asm volatile("" : "+v"(wib0), "+v"(wib1), "+v"(wib2), "+v"(basb));

        // x-term for step s+1 (independent of h-chain; fills latency slots)
        float xgaN = fmaf(wia2, x2, fmaf(wia1, x1, fmaf(wia0, x0, basa)));
        float xgbN = fmaf(wib2, x2, fmaf(wib1, x1, fmaf(wib0, x0, basb)));
        // prefetch x for step s+2 (uniform addr)
        {
            int sn = (s + 2 < T_SEQ) ? (s + 2) : (T_SEQ - 1);
            int tn = dir ? (T_SEQ - 1 - sn) : sn;
            x0 = xb[tn*3+0]; x1 = xb[tn*3+1]; x2 = xb[tn*3+2];
        }

        float a0 = xga, a1 = 0.f, a2 = 0.f, a3 = 0.f;
        float c0 = xgb, c1 = 0.f, c2 = 0.f, c3 = 0.f;
        HFMA_ALL
        float za = (a0 + a1) + (a2 + a3);
        float zb = (c0 + c1) + (c2 + c3);

        // half-swap + branch-free gate select
        float fa = swap_half(za);
        float fb = swap_half(zb);
        float zi = hi ? fa : za;
        float zf = hi ? za : fa;
        float zg = hi ? fb : zb;
        float zo = hi ? zb : fb;

        c = sigf(zf) * c + sigf(zi) * tanhf_fast(zg);
        float h = sigf(zo) * tanhf_fast(c);

        if (hi == 0) outp[(size_t)t * 64] = h;

        // broadcast new h to uniform regs for next step
#pragma unroll
        for (int k = 0; k < HID; ++k) hs[k] = rdlane(h, k);

        xga = xgaN; xgb = xgbN;
        t += step;
    }
}

// =====================================================================
// gx1 = bias + h0 @ w_ih_l1^T for both directions. One block per t.
// Thread owns one output col (d,j); its 64 W values live in named VGPR
// scalars (keepalive-forced); A rows double-buffered in registers.
// =====================================================================
#define WRLOAD_ALL(w_)                                                       \
    WGRP(wr0_,  w_, j*64+ 0) WGRP(wr1_,  w_, j*64+ 4)                        \
    WGRP(wr2_,  w_, j*64+ 8) WGRP(wr3_,  w_, j*64+12)                        \
    WGRP(wr4_,  w_, j*64+16) WGRP(wr5_,  w_, j*64+20)                        \
    WGRP(wr6_,  w_, j*64+24) WGRP(wr7_,  w_, j*64+28)                        \
    WGRP(wr8_,  w_, j*64+32) WGRP(wr9_,  w_, j*64+36)                        \
    WGRP(wr10_, w_, j*64+40) WGRP(wr11_, w_, j*64+44)                        \
    WGRP(wr12_, w_, j*64+48) WGRP(wr13_, w_, j*64+52)                        \
    WGRP(wr14_, w_, j*64+56) WGRP(wr15_, w_, j*64+60)

#define KEEPWR                                                               \
    KEEP4(wr0_)  KEEP4(wr1_)  KEEP4(wr2_)  KEEP4(wr3_)                       \
    KEEP4(wr4_)  KEEP4(wr5_)  KEEP4(wr6_)  KEEP4(wr7_)                       \
    KEEP4(wr8_)  KEEP4(wr9_)  KEEP4(wr10_) KEEP4(wr11_)                      \
    KEEP4(wr12_) KEEP4(wr13_) KEEP4(wr14_) KEEP4(wr15_)

#define GF1(ARR, q, NM)                                                      \
    a0 = fmaf(ARR[q].x, NM##0, a0); a1 = fmaf(ARR[q].y, NM##1, a1);          \
    a2 = fmaf(ARR[q].z, NM##2, a2); a3 = fmaf(ARR[q].w, NM##3, a3);

#define GFALL(ARR)                                                           \
    GF1(ARR, 0, wr0_)  GF1(ARR, 1, wr1_)  GF1(ARR, 2, wr2_)                  \
    GF1(ARR, 3, wr3_)  GF1(ARR, 4, wr4_)  GF1(ARR, 5, wr5_)                  \
    GF1(ARR, 6, wr6_)  GF1(ARR, 7, wr7_)  GF1(ARR, 8, wr8_)                  \
    GF1(ARR, 9, wr9_)  GF1(ARR,10, wr10_) GF1(ARR,11, wr11_)                 \
    GF1(ARR,12, wr12_) GF1(ARR,13, wr13_) GF1(ARR,14, wr14_)                 \
    GF1(ARR,15, wr15_)

__global__ void __launch_bounds__(256)
__attribute__((amdgpu_waves_per_eu(2, 2)))
gx1_gemm(const float* __restrict__ h0,     // [B][T][64]
         const float* __restrict__ w_f, const float* __restrict__ bi_f, const float* __restrict__ bh_f,
         const float* __restrict__ w_b, const float* __restrict__ bi_b, const float* __restrict__ bh_b,
         float* __restrict__ gxo)          // [2][T][B][128]
{
    const int tid = threadIdx.x;
    const int d = tid >> 7, j = tid & 127;
    const int t = blockIdx.x;

    const float* w = d ? w_b : w_f;
    WRLOAD_ALL(w)
    const float bias = d ? (bi_b[j] + bh_b[j]) : (bi_f[j] + bh_f[j]);

    float* outp = gxo + ((size_t)d * T_SEQ + t) * ((size_t)BATCH * 128) + j;
    const float* base = h0 + (size_t)t * 64;       // + b * (T*64)

    float4 A[16], B4[16];
#pragma unroll
    for (int q = 0; q < 16; ++q) A[q] = LD4(base + q*4);   // b=0

    for (int b = 0; b < BATCH; b += 2) {
        KEEPWR
        {   // prefetch row b+1
            const float* p = base + (size_t)(b + 1) * (T_SEQ * 64);
#pragma unroll
            for (int q = 0; q < 16; ++q) B4[q] = LD4(p + q*4);
        }
        {   // compute row b
            float a0 = bias, a1 = 0.f, a2 = 0.f, a3 = 0.f;
            GFALL(A)
            outp[(size_t)b * 128] = (a0 + a1) + (a2 + a3);
        }
        if (b + 2 < BATCH) {   // prefetch row b+2
            const float* p = base + (size_t)(b + 2) * (T_SEQ * 64);
#pragma unroll
            for (int q = 0; q < 16; ++q) A[q] = LD4(p + q*4);
        }
        {   // compute row b+1
            float a0 = bias, a1 = 0.f, a2 = 0.f, a3 = 0.f;
            GFALL(B4)
            outp[(size_t)(b + 1) * 128] = (a0 + a1) + (a2 + a3);
        }
    }
}

// =====================================================================
// LSTM layer 1: input term from precomputed gx1, distance-2 prefetch.
// =====================================================================
__global__ void __launch_bounds__(64)
__attribute__((amdgpu_waves_per_eu(1, 1)))
lstm_l1(const float* __restrict__ gx,      // [2][T][B][128]
        const float* __restrict__ whh_f, const float* __restrict__ whh_b,
        float* __restrict__ hn)            // [B][64]
{
    const int l   = threadIdx.x;
    const int u   = l & 31;
    const int hi  = l >> 5;
    const int bid = blockIdx.x;
    const int dir = bid >> 8;
    const int b   = bid & 255;

    const float* whh = dir ? whh_b : whh_f;
    const int ra = l, rb = 64 + l;

    WLOAD_ALL(whh)

    float hs[HID];
#pragma unroll
    for (int k = 0; k < HID; ++k) hs[k] = 0.0f;
    float c = 0.0f;

    const size_t TS = (size_t)BATCH * 128;
    const float* gp = gx + ((size_t)dir * T_SEQ * BATCH + b) * 128;

    int t = dir ? (T_SEQ - 1) : 0;
    const int step = dir ? -1 : 1;

    // distance-2 prefetch pipeline: ga0/gb0 for step s, ga1/gb1 for s+1
    float ga0 = gp[(size_t)t * TS + ra];
    float gb0 = gp[(size_t)t * TS + rb];
    float ga1, gb1;
    {
        int t1 = t + step;
        ga1 = gp[(size_t)t1 * TS + ra];
        gb1 = gp[(size_t)t1 * TS + rb];
    }

    float h = 0.0f;
    for (int s = 0; s < T_SEQ; ++s) {
        KEEPW

        // issue loads for step s+2 (coalesced 256B per wave)
        float gaN, gbN;
        {
            int sn = (s + 2 < T_SEQ) ? (s + 2) : (T_SEQ - 1);
            int tn = dir ? (T_SEQ - 1 - sn) : sn;
            gaN = gp[(size_t)tn * TS + ra];
            gbN = gp[(size_t)tn * TS + rb];
        }

        float a0 = ga0, a1 = 0.f, a2 = 0.f, a3 = 0.f;
        float c0 = gb0, c1 = 0.f, c2 = 0.f, c3 = 0.f;
        HFMA_ALL
        float za = (a0 + a1) + (a2 + a3);
        float zb = (c0 + c1) + (c2 + c3);

        float fa = swap_half(za);
        float fb = swap_half(zb);
        float zi = hi ? fa : za;
        float zf = hi ? za : fa;
        float zg = hi ? fb : zb;
        float zo = hi ? zb : fb;

        c = sigf(zf) * c + sigf(zi) * tanhf_fast(zg);
        h = sigf(zo) * tanhf_fast(c);

#pragma unroll
        for (int k = 0; k < HID; ++k) hs[k] = rdlane(h, k);

        ga0 = ga1; gb0 = gb1; ga1 = gaN; gb1 = gbN;
        t += step;
    }
    if (hi == 0) hn[(size_t)b * 64 + dir * HID + u] = h;
}

// =====================================================================
// Classifier: relu(hn @ wc1^T + bc1) @ wc2^T + bc2. One block per batch.
// =====================================================================
__global__ void __launch_bounds__(64)
classifier(const float* __restrict__ hn,   // [B][64]
           const float* __restrict__ wc1,  // [32][64]
           const float* __restrict__ bc1,  // [32]
           const float* __restrict__ wc2,  // [2][32]
           const float* __restrict__ bc2,  // [2]
           float* __restrict__ out)        // [B][2]
{
    const int b = blockIdx.x, tid = threadIdx.x;
    __shared__ float hsm[64];
    __shared__ float hidden[32];
    hsm[tid] = hn[(size_t)b * 64 + tid];
    __syncthreads();
    if (tid < 32) {
        float a = bc1[tid];
#pragma unroll
        for (int k = 0; k < 64; ++k) a = fmaf(wc1[tid*64 + k], hsm[k], a);
        hidden[tid] = fmaxf(a, 0.0f);
    }
    __syncthreads();
    if (tid < 2) {
        float a = bc2[tid];
#pragma unroll
        for (int k = 0; k < 32; ++k) a = fmaf(wc2[tid*32 + k], hidden[k], a);
        out[(size_t)b * 2 + tid] = a;
    }
}

// =====================================================================
extern "C" void kernel_launch(void* const* d_in, const int* in_sizes, int n_in,
                              void* d_out, int out_size, void* d_ws, size_t ws_size,
                              hipStream_t stream) {
    const float* x        = (const float*)d_in[0];
    const float* w_ih_l0f = (const float*)d_in[1];
    const float* w_hh_l0f = (const float*)d_in[2];
    const float* b_ih_l0f = (const float*)d_in[3];
    const float* b_hh_l0f = (const float*)d_in[4];
    const float* w_ih_l0b = (const float*)d_in[5];
    const float* w_hh_l0b = (const float*)d_in[6];
    const float* b_ih_l0b = (const float*)d_in[7];
    const float* b_hh_l0b = (const float*)d_in[8];
    const float* w_ih_l1f = (const float*)d_in[9];
    const float* w_hh_l1f = (const float*)d_in[10];
    const float* b_ih_l1f = (const float*)d_in[11];
    const float* b_hh_l1f = (const float*)d_in[12];
    const float* w_ih_l1b = (const float*)d_in[13];
    const float* w_hh_l1b = (const float*)d_in[14];
    const float* b_ih_l1b = (const float*)d_in[15];
    const float* b_hh_l1b = (const float*)d_in[16];
    const float* wc1      = (const float*)d_in[17];
    const float* bc1      = (const float*)d_in[18];
    const float* wc2      = (const float*)d_in[19];
    const float* bc2      = (const float*)d_in[20];
    float* out = (float*)d_out;

    // workspace layout (bytes):
    //   h0  [B][T][64]      : 33,554,432
    //   gx1 [2][T][B][128]  : 134,217,728
    //   hn  [B][64]         : 65,536
    char* ws = (char*)d_ws;
    float* h0  = (float*)(ws);
    float* gx1 = (float*)(ws + 33554432);
    float* hn  = (float*)(ws + 33554432 + 134217728);

    lstm_l0<<<dim3(512), dim3(64), 0, stream>>>(
        x, w_ih_l0f, w_hh_l0f, b_ih_l0f, b_hh_l0f,
           w_ih_l0b, w_hh_l0b, b_ih_l0b, b_hh_l0b, h0);

    gx1_gemm<<<dim3(T_SEQ), dim3(256), 0, stream>>>(
        h0, w_ih_l1f, b_ih_l1f, b_hh_l1f,
            w_ih_l1b, b_ih_l1b, b_hh_l1b, gx1);

    lstm_l1<<<dim3(512), dim3(64), 0, stream>>>(
        gx1, w_hh_l1f, w_hh_l1b, hn);

    classifier<<<dim3(BATCH), dim3(64), 0, stream>>>(
        hn, wc1, bc1, wc2, bc2, out);
}